// Round 1
// baseline (239.568 us; speedup 1.0000x reference)
//
#include <hip/hip_runtime.h>
#include <math.h>

#define NB 4
#define NL 128
#define NT 512
#define NS 128
#define HD 256
#define TILE_M 64
#define NTHREADS 512
#define GRID 256
#define NTILES (NB*NL*NT/TILE_M)          // 4096
#define TILES_PER_BLOCK (NTILES/GRID)     // 16

typedef __bf16 bf16x8 __attribute__((ext_vector_type(8)));
typedef __bf16 bf16x4 __attribute__((ext_vector_type(4)));
typedef float  f32x4  __attribute__((ext_vector_type(4)));

__device__ __forceinline__ int swz(int row, int colByte) {
    // logical byte addr row*512 + colByte, XOR-swizzled to spread rows across banks
    return ((row << 9) + colByte) ^ ((row & 7) << 4);
}

__global__ __launch_bounds__(NTHREADS) void fused_gvp_kernel(
    const float* __restrict__ indice,   // [B,3,NL,NT]
    const float* __restrict__ lpos,     // [B,NL,3]
    const float* __restrict__ tpos,     // [B,NT,3]
    const float* __restrict__ lrad,     // [B,NL]
    const float* __restrict__ trad,     // [B,NT]
    const float* __restrict__ lnm,      // [B,NL]
    const float* __restrict__ tnm,      // [B,NT]
    const float* __restrict__ hcat,     // [B,NL,NT,HD]
    const float* __restrict__ AW1, const float* __restrict__ Ab1,
    const float* __restrict__ AW2, const float* __restrict__ Ab2,
    const float* __restrict__ BW1, const float* __restrict__ Bb1,
    const float* __restrict__ BW2, const float* __restrict__ Bb2,
    float* __restrict__ ws)             // [B*4] partial sums (pre-zeroed)
{
    __shared__ __align__(16) __bf16 hbuf[2][TILE_M * HD];  // 64 KiB, swizzled
    __shared__ float part[8][TILE_M];                      // per-wave relu-dot partials

    const int tid  = threadIdx.x;
    const int wv   = tid >> 6;
    const int lane = tid & 63;
    const int kg   = lane >> 4;        // 0..3 (K-group within fragment)

    // ---- per-wave weight fragments: wave wv owns 32 hidden cols ----
    const bool  isA = (wv < 4);
    const float* W1 = isA ? AW1 : BW1;
    const float* W2 = isA ? AW2 : BW2;
    const float* b1 = isA ? Ab1 : Bb1;
    const int nbase = (wv & 3) * 32;

    bf16x8 wreg[2][8];     // [n-frag][k-step]
    float  b1v[2], w2v[2];
    #pragma unroll
    for (int nf = 0; nf < 2; ++nf) {
        int n = nbase + nf * 16 + (lane & 15);
        b1v[nf] = b1[n];
        w2v[nf] = W2[n];
        #pragma unroll
        for (int kk = 0; kk < 8; ++kk) {
            int k0 = kk * 32 + kg * 8;
            bf16x8 wvv;
            #pragma unroll
            for (int i = 0; i < 8; ++i)
                wvv[i] = (__bf16)W1[(k0 + i) * NS + n];
            wreg[nf][kk] = wvv;
        }
    }

    const int tile0 = blockIdx.x * TILES_PER_BLOCK;

    // ---- prologue: stage tile0 into hbuf[0] ----
    float4 stg[8];
    {
        const float* src = hcat + (size_t)tile0 * (TILE_M * HD);
        #pragma unroll
        for (int i = 0; i < 8; ++i)
            stg[i] = *(const float4*)(src + tid * 4 + i * 2048);
        #pragma unroll
        for (int i = 0; i < 8; ++i) {
            int row = (tid >> 6) + i * 8;
            int cb  = (tid & 63) * 8;   // byte col offset
            bf16x4 p;
            p[0] = (__bf16)stg[i].x; p[1] = (__bf16)stg[i].y;
            p[2] = (__bf16)stg[i].z; p[3] = (__bf16)stg[i].w;
            *(bf16x4*)((char*)&hbuf[0][0] + swz(row, cb)) = p;
        }
    }

    for (int it = 0; it < TILES_PER_BLOCK; ++it) {
        const int tt = tile0 + it;
        __syncthreads();   // barrier A: hbuf[it&1] populated; part[] free for rewrite

        // issue next tile's global loads now; they complete during the K-loop
        if (it + 1 < TILES_PER_BLOCK) {
            const float* src = hcat + (size_t)(tt + 1) * (TILE_M * HD);
            #pragma unroll
            for (int i = 0; i < 8; ++i)
                stg[i] = *(const float4*)(src + tid * 4 + i * 2048);
        }

        // ---- MFMA K-loop: rows 0..63 x this wave's 32 cols ----
        f32x4 acc[4][2] = {};
        const char* lb = (const char*)&hbuf[it & 1][0];
        #pragma unroll
        for (int kk = 0; kk < 8; ++kk) {
            int kb2 = (kk * 32 + kg * 8) * 2;
            #pragma unroll
            for (int m = 0; m < 4; ++m) {
                int row = m * 16 + (lane & 15);
                bf16x8 a = *(const bf16x8*)(lb + swz(row, kb2));
                acc[m][0] = __builtin_amdgcn_mfma_f32_16x16x32_bf16(a, wreg[0][kk], acc[m][0], 0, 0, 0);
                acc[m][1] = __builtin_amdgcn_mfma_f32_16x16x32_bf16(a, wreg[1][kk], acc[m][1], 0, 0, 0);
            }
        }

        // ---- relu + dot(W2) partial per row, reduced over this wave's 16-lane col groups ----
        #pragma unroll
        for (int m = 0; m < 4; ++m) {
            #pragma unroll
            for (int j = 0; j < 4; ++j) {
                float p = fmaxf(acc[m][0][j] + b1v[0], 0.f) * w2v[0]
                        + fmaxf(acc[m][1][j] + b1v[1], 0.f) * w2v[1];
                p += __shfl_xor(p, 1, 64);
                p += __shfl_xor(p, 2, 64);
                p += __shfl_xor(p, 4, 64);
                p += __shfl_xor(p, 8, 64);
                if ((lane & 15) == 0) part[wv][m * 16 + kg * 4 + j] = p;
            }
        }

        __syncthreads();   // barrier B: part[] ready; stg loads drained

        // convert + write next tile into the other buffer
        if (it + 1 < TILES_PER_BLOCK) {
            char* lw = (char*)&hbuf[(it + 1) & 1][0];
            #pragma unroll
            for (int i = 0; i < 8; ++i) {
                int row = (tid >> 6) + i * 8;
                int cb  = (tid & 63) * 8;
                bf16x4 p;
                p[0] = (__bf16)stg[i].x; p[1] = (__bf16)stg[i].y;
                p[2] = (__bf16)stg[i].z; p[3] = (__bf16)stg[i].w;
                *(bf16x4*)(lw + swz(row, cb)) = p;
            }
        }

        // ---- scalar epilogue on wave 0: one lane per row ----
        if (tid < 64) {
            const int r = lane;
            float sA = Ab2[0], sB = Bb2[0];
            #pragma unroll
            for (int w8 = 0; w8 < 4; ++w8) {
                sA += part[w8][r];
                sB += part[w8 + 4][r];
            }
            float aw = 0.0178f + 0.0178f / (1.f + expf(-sA));  // sigmoid*(MAX-MIN)+MIN
            float bp = tanhf(sB) * 0.2f;

            const int tbase = tt * TILE_M;
            const int b  = tbase >> 16;            // / (NL*NT)
            const int rm = tbase & 65535;
            const int l  = rm >> 9;                // / NT
            const int t  = (rm & 511) + r;

            const float* lp = lpos + ((size_t)b * NL + l) * 3;
            const float* tp = tpos + ((size_t)b * NT + t) * 3;
            float dx = lp[0] - tp[0], dy = lp[1] - tp[1], dz = lp[2] - tp[2];
            float dm = sqrtf(dx * dx + dy * dy + dz * dz + 1e-10f);
            if (dm < 0.5f) dm = 1e10f;

            float dm0 = lrad[b * NL + l] + trad[b * NT + t] + bp;
            float ddm = dm - dm0;

            const size_t ib = (((size_t)b * 3) * NL + l) * NT + t;
            float i0 = indice[ib];
            float i1 = indice[ib + (size_t)NL * NT];
            float i2 = indice[ib + 2 * (size_t)NL * NT];

            const float kInv = -1.f / 0.7f;
            float ehb = fminf(fmaxf(ddm * i0 * kInv, 0.f), 1.f);
            float emt = fminf(fmaxf(ddm * i1 * kInv, 0.f), 1.f);
            float ehp = fminf(fmaxf((1.5f - ddm) * i2, 0.f), 1.f);

            float dm0v = (dm0 < 1e-4f) ? 1.f : dm0;
            float ratio = dm0v / dm;
            float r2 = ratio * ratio;
            float r6 = r2 * r2 * r2;
            float ve = fminf(r6 * r6 - 2.f * r6, 100.f);
            ve *= lnm[b * NL + l] * tnm[b * NT + t];
            float evdw = aw * ve;

            #pragma unroll
            for (int off = 32; off > 0; off >>= 1) {
                evdw += __shfl_down(evdw, off, 64);
                ehb  += __shfl_down(ehb,  off, 64);
                emt  += __shfl_down(emt,  off, 64);
                ehp  += __shfl_down(ehp,  off, 64);
            }
            if (r == 0) {
                atomicAdd(ws + b * 4 + 0, evdw);
                atomicAdd(ws + b * 4 + 1, ehb);
                atomicAdd(ws + b * 4 + 2, emt);
                atomicAdd(ws + b * 4 + 3, ehp);
            }
        }
    }
}

__global__ void finalize_kernel(const float* __restrict__ ws,
                                const float* __restrict__ rotor,
                                const float* __restrict__ hbc,
                                const float* __restrict__ hyc,
                                const float* __restrict__ rcc,
                                float* __restrict__ out)
{
    int b = threadIdx.x;
    if (b < NB) {
        float s   = 1.f / (1.f + rcc[0] * rcc[0] * rotor[b]);
        float hb2 = hbc[0] * hbc[0];
        float hy2 = hyc[0] * hyc[0];
        out[b * 4 + 0] = ws[b * 4 + 0] * s;
        out[b * 4 + 1] = -hb2 * ws[b * 4 + 1] * s;
        out[b * 4 + 2] = -hb2 * ws[b * 4 + 2] * s;
        out[b * 4 + 3] = -hy2 * ws[b * 4 + 3] * s;
    }
}

extern "C" void kernel_launch(void* const* d_in, const int* in_sizes, int n_in,
                              void* d_out, int out_size, void* d_ws, size_t ws_size,
                              hipStream_t stream)
{
    const float* indice = (const float*)d_in[0];
    const float* lpos   = (const float*)d_in[1];
    const float* tpos   = (const float*)d_in[2];
    const float* rotor  = (const float*)d_in[3];
    const float* lrad   = (const float*)d_in[4];
    const float* trad   = (const float*)d_in[5];
    const float* lnm    = (const float*)d_in[6];
    const float* tnm    = (const float*)d_in[7];
    const float* hcat   = (const float*)d_in[8];
    const float* AW1    = (const float*)d_in[9];
    const float* Ab1    = (const float*)d_in[10];
    const float* AW2    = (const float*)d_in[11];
    const float* Ab2    = (const float*)d_in[12];
    const float* BW1    = (const float*)d_in[13];
    const float* Bb1    = (const float*)d_in[14];
    const float* BW2    = (const float*)d_in[15];
    const float* Bb2    = (const float*)d_in[16];
    const float* hbc    = (const float*)d_in[17];
    const float* hyc    = (const float*)d_in[18];
    const float* rcc    = (const float*)d_in[19];

    float* ws  = (float*)d_ws;
    float* out = (float*)d_out;

    hipMemsetAsync(ws, 0, 16 * sizeof(float), stream);
    hipLaunchKernelGGL(fused_gvp_kernel, dim3(GRID), dim3(NTHREADS), 0, stream,
                       indice, lpos, tpos, lrad, trad, lnm, tnm, hcat,
                       AW1, Ab1, AW2, Ab2, BW1, Bb1, BW2, Bb2, ws);
    hipLaunchKernelGGL(finalize_kernel, dim3(1), dim3(64), 0, stream,
                       ws, rotor, hbc, hyc, rcc, out);
}

// Round 2
// 91.631 us; speedup vs baseline: 2.6145x; 2.6145x over previous
//
#include <hip/hip_runtime.h>
#include <math.h>

#define NB 4
#define NL 128
#define NT 512
#define NS 128
#define HD 256
#define TILE_M 32
#define NTHREADS 512
#define TPB 16                      // tiles per block
#define GRID 512                    // (NB*NL*NT/TILE_M)/TPB = 8192/16

typedef __bf16 bf16x8 __attribute__((ext_vector_type(8)));
typedef __bf16 bf16x4 __attribute__((ext_vector_type(4)));
typedef float  f32x4  __attribute__((ext_vector_type(4)));

__global__ __launch_bounds__(NTHREADS) void fused_gvp_kernel(
    const float* __restrict__ indice,   // [B,3,NL,NT]
    const float* __restrict__ lpos,     // [B,NL,3]
    const float* __restrict__ tpos,     // [B,NT,3]
    const float* __restrict__ lrad,     // [B,NL]
    const float* __restrict__ trad,     // [B,NT]
    const float* __restrict__ lnm,      // [B,NL]
    const float* __restrict__ tnm,      // [B,NT]
    const float* __restrict__ hcat,     // [B,NL,NT,HD]
    const float* __restrict__ AW1, const float* __restrict__ Ab1,
    const float* __restrict__ AW2, const float* __restrict__ Ab2,
    const float* __restrict__ BW1, const float* __restrict__ Bb1,
    const float* __restrict__ BW2, const float* __restrict__ Bb2,
    float* __restrict__ ws)             // [B*4] raw sums (pre-zeroed)
{
    __shared__ __align__(16) __bf16 hbuf[2][TILE_M * HD];   // 32 KiB, swizzled
    __shared__ __align__(16) float  part[TPB][TILE_M][8];   // 16 KiB
    __shared__ float red[8][4];

    const int tid  = threadIdx.x;
    const int wv   = tid >> 6;
    const int lane = tid & 63;
    const int l15  = lane & 15;
    const int kg   = lane >> 4;

    const size_t base = (size_t)blockIdx.x * (TPB * TILE_M * HD);

    // ---- issue tile-0 loads first (latency hides under weight setup) ----
    float4 stg[4];
    {
        const float* src = hcat + base;
        #pragma unroll
        for (int i = 0; i < 4; ++i)
            stg[i] = *(const float4*)(src + ((tid >> 6) + i * 8) * HD + (tid & 63) * 4);
    }

    // ---- per-wave weight fragments: wave wv owns 32 hidden cols of A or B MLP ----
    const bool  isA = (wv < 4);
    const float* W1 = isA ? AW1 : BW1;
    const float* W2 = isA ? AW2 : BW2;
    const float* b1 = isA ? Ab1 : Bb1;
    const int nbase = (wv & 3) * 32;

    bf16x8 wreg[2][8];
    float  b1v[2], w2v[2];
    #pragma unroll
    for (int nf = 0; nf < 2; ++nf) {
        int n = nbase + nf * 16 + l15;
        b1v[nf] = b1[n];
        w2v[nf] = W2[n];
        #pragma unroll
        for (int kk = 0; kk < 8; ++kk) {
            int k0 = kk * 32 + kg * 8;
            bf16x8 wvv;
            #pragma unroll
            for (int i = 0; i < 8; ++i)
                wvv[i] = (__bf16)W1[(k0 + i) * NS + n];
            wreg[nf][kk] = wvv;
        }
    }

    // ---- write tile 0 into hbuf[0] (swizzled) ----
    #pragma unroll
    for (int i = 0; i < 4; ++i) {
        int row = (tid >> 6) + i * 8;
        int cb  = (tid & 63) * 8;
        bf16x4 p;
        p[0] = (__bf16)stg[i].x; p[1] = (__bf16)stg[i].y;
        p[2] = (__bf16)stg[i].z; p[3] = (__bf16)stg[i].w;
        *(bf16x4*)((char*)&hbuf[0][0] + row * 512 + (cb ^ ((row & 15) << 4))) = p;
    }

    for (int it = 0; it < TPB; ++it) {
        __syncthreads();   // hbuf[it&1] ready; all reads of hbuf[(it+1)&1] from it-1 done

        // prefetch tile it+1 (completes during K-loop + reduce)
        if (it + 1 < TPB) {
            const float* src = hcat + base + (size_t)(it + 1) * (TILE_M * HD);
            #pragma unroll
            for (int i = 0; i < 4; ++i)
                stg[i] = *(const float4*)(src + ((tid >> 6) + i * 8) * HD + (tid & 63) * 4);
        }

        // ---- MFMA K-loop: 32 rows x this wave's 32 cols, K=256 ----
        f32x4 acc[2][2] = {};
        const char* lb = (const char*)&hbuf[it & 1][0];
        #pragma unroll
        for (int kk = 0; kk < 8; ++kk) {
            #pragma unroll
            for (int m = 0; m < 2; ++m) {
                int row = m * 16 + l15;
                bf16x8 a = *(const bf16x8*)(lb + row * 512 + ((kk * 64 + kg * 16) ^ ((row & 15) << 4)));
                acc[m][0] = __builtin_amdgcn_mfma_f32_16x16x32_bf16(a, wreg[0][kk], acc[m][0], 0, 0, 0);
                acc[m][1] = __builtin_amdgcn_mfma_f32_16x16x32_bf16(a, wreg[1][kk], acc[m][1], 0, 0, 0);
            }
        }

        // ---- relu + W2-dot partial per row; reduce over 16-lane col groups ----
        #pragma unroll
        for (int m = 0; m < 2; ++m) {
            #pragma unroll
            for (int j = 0; j < 4; ++j) {
                float p = fmaxf(acc[m][0][j] + b1v[0], 0.f) * w2v[0]
                        + fmaxf(acc[m][1][j] + b1v[1], 0.f) * w2v[1];
                p += __shfl_xor(p, 1, 64);
                p += __shfl_xor(p, 2, 64);
                p += __shfl_xor(p, 4, 64);
                p += __shfl_xor(p, 8, 64);
                if (l15 == 0) part[it][m * 16 + kg * 4 + j][wv] = p;
            }
        }

        // ---- convert + write tile it+1 into other buffer (vmcnt drains here) ----
        if (it + 1 < TPB) {
            char* lw = (char*)&hbuf[(it + 1) & 1][0];
            #pragma unroll
            for (int i = 0; i < 4; ++i) {
                int row = (tid >> 6) + i * 8;
                int cb  = (tid & 63) * 8;
                bf16x4 p;
                p[0] = (__bf16)stg[i].x; p[1] = (__bf16)stg[i].y;
                p[2] = (__bf16)stg[i].z; p[3] = (__bf16)stg[i].w;
                *(bf16x4*)(lw + row * 512 + (cb ^ ((row & 15) << 4))) = p;
            }
        }
    }

    __syncthreads();   // all part[] slots written

    // ---- epilogue: one pair-row per thread (block covers one (b,l), t=tid) ----
    {
        const f32x4* pp = (const f32x4*)&part[tid >> 5][tid & 31][0];
        f32x4 pa = pp[0], pb = pp[1];
        float sA = Ab2[0] + pa[0] + pa[1] + pa[2] + pa[3];
        float sB = Bb2[0] + pb[0] + pb[1] + pb[2] + pb[3];

        float aw = 0.0178f + 0.0178f / (1.f + expf(-sA));   // sigmoid*(MAX-MIN)+MIN
        float bp = tanhf(sB) * 0.2f;

        const int g = blockIdx.x * (TPB * TILE_M) + tid;    // global pair index
        const int b = g >> 16;
        const int l = (g >> 9) & 127;                       // uniform per block
        const int t = g & 511;                              // == tid

        const float* lp = lpos + ((size_t)b * NL + l) * 3;
        const float* tp = tpos + ((size_t)b * NT + t) * 3;
        float dx = lp[0] - tp[0], dy = lp[1] - tp[1], dz = lp[2] - tp[2];
        float dm = sqrtf(dx * dx + dy * dy + dz * dz + 1e-10f);
        if (dm < 0.5f) dm = 1e10f;

        float dm0 = lrad[b * NL + l] + trad[b * NT + t] + bp;
        float ddm = dm - dm0;

        const size_t ib = (((size_t)b * 3) * NL + l) * NT + t;
        float i0 = indice[ib];
        float i1 = indice[ib + (size_t)NL * NT];
        float i2 = indice[ib + 2 * (size_t)NL * NT];

        const float kInv = -1.f / 0.7f;
        float ehb = fminf(fmaxf(ddm * i0 * kInv, 0.f), 1.f);
        float emt = fminf(fmaxf(ddm * i1 * kInv, 0.f), 1.f);
        float ehp = fminf(fmaxf((1.5f - ddm) * i2, 0.f), 1.f);

        float dm0v = (dm0 < 1e-4f) ? 1.f : dm0;
        float ratio = dm0v / dm;
        float r2 = ratio * ratio;
        float r6 = r2 * r2 * r2;
        float ve = fminf(r6 * r6 - 2.f * r6, 100.f);
        ve *= lnm[b * NL + l] * tnm[b * NT + t];
        float evdw = aw * ve;

        // wave reduce 4 values
        #pragma unroll
        for (int off = 32; off > 0; off >>= 1) {
            evdw += __shfl_xor(evdw, off, 64);
            ehb  += __shfl_xor(ehb,  off, 64);
            emt  += __shfl_xor(emt,  off, 64);
            ehp  += __shfl_xor(ehp,  off, 64);
        }
        if (lane == 0) {
            red[wv][0] = evdw; red[wv][1] = ehb;
            red[wv][2] = emt;  red[wv][3] = ehp;
        }
    }
    __syncthreads();
    if (tid < 4) {
        float v = 0.f;
        #pragma unroll
        for (int w = 0; w < 8; ++w) v += red[w][tid];
        atomicAdd(ws + (blockIdx.x >> 7) * 4 + tid, v);
    }
}

__global__ void finalize_kernel(const float* __restrict__ ws,
                                const float* __restrict__ rotor,
                                const float* __restrict__ hbc,
                                const float* __restrict__ hyc,
                                const float* __restrict__ rcc,
                                float* __restrict__ out)
{
    int b = threadIdx.x;
    if (b < NB) {
        float s   = 1.f / (1.f + rcc[0] * rcc[0] * rotor[b]);
        float hb2 = hbc[0] * hbc[0];
        float hy2 = hyc[0] * hyc[0];
        out[b * 4 + 0] = ws[b * 4 + 0] * s;
        out[b * 4 + 1] = -hb2 * ws[b * 4 + 1] * s;
        out[b * 4 + 2] = -hb2 * ws[b * 4 + 2] * s;
        out[b * 4 + 3] = -hy2 * ws[b * 4 + 3] * s;
    }
}

extern "C" void kernel_launch(void* const* d_in, const int* in_sizes, int n_in,
                              void* d_out, int out_size, void* d_ws, size_t ws_size,
                              hipStream_t stream)
{
    const float* indice = (const float*)d_in[0];
    const float* lpos   = (const float*)d_in[1];
    const float* tpos   = (const float*)d_in[2];
    const float* rotor  = (const float*)d_in[3];
    const float* lrad   = (const float*)d_in[4];
    const float* trad   = (const float*)d_in[5];
    const float* lnm    = (const float*)d_in[6];
    const float* tnm    = (const float*)d_in[7];
    const float* hcat   = (const float*)d_in[8];
    const float* AW1    = (const float*)d_in[9];
    const float* Ab1    = (const float*)d_in[10];
    const float* AW2    = (const float*)d_in[11];
    const float* Ab2    = (const float*)d_in[12];
    const float* BW1    = (const float*)d_in[13];
    const float* Bb1    = (const float*)d_in[14];
    const float* BW2    = (const float*)d_in[15];
    const float* Bb2    = (const float*)d_in[16];
    const float* hbc    = (const float*)d_in[17];
    const float* hyc    = (const float*)d_in[18];
    const float* rcc    = (const float*)d_in[19];

    float* ws  = (float*)d_ws;
    float* out = (float*)d_out;

    hipMemsetAsync(ws, 0, 16 * sizeof(float), stream);
    hipLaunchKernelGGL(fused_gvp_kernel, dim3(GRID), dim3(NTHREADS), 0, stream,
                       indice, lpos, tpos, lrad, trad, lnm, tnm, hcat,
                       AW1, Ab1, AW2, Ab2, BW1, Bb1, BW2, Bb2, ws);
    hipLaunchKernelGGL(finalize_kernel, dim3(1), dim3(64), 0, stream,
                       ws, rotor, hbc, hyc, rcc, out);
}